// Round 6
// baseline (192161.243 us; speedup 1.0000x reference)
//
#include <hip/hip_runtime.h>
#include <math.h>

#define Bq 256
#define Tq 200
#define INq 33
#define Hq 2048
#define OUTq 4

#define BK 32
#define NST 16          // stages per K-quarter: 512/32

#define DOT4(ACC, Av, Bv) \
  ACC = fmaf((Av).x, (Bv).x, ACC); ACC = fmaf((Av).y, (Bv).y, ACC); \
  ACC = fmaf((Av).z, (Bv).z, ACC); ACC = fmaf((Av).w, (Bv).w, ACC)

// LDS (float offsets):
//  Bbuf[kq][buf] : [64 cols][33]  at (kq*2+buf)*2112   -> 16896 floats
//  Red (post-K-loop, overlaps Bbuf): 3*32*64 = 6144 at 0
//  proj scratch: 32 floats at 16896
#define SMEMF 16928

// ---------------------------------------------------------------------------
// tail: out_o[r, tp, :] = softmax(h_row @ Wh2o^T) for the final step
// ---------------------------------------------------------------------------
__global__ __launch_bounds__(256) void proj_tail(
    const float* __restrict__ hbase, size_t rstride,
    const float* __restrict__ Wh2o, float* __restrict__ out_o, int tp)
{
  const int tid = threadIdx.x;
  const int r  = blockIdx.x * 64 + (tid >> 2);
  const int p4 = tid & 3;
  const float* hp = hbase + (size_t)r * rstride;
  float a0 = 0.f, a1 = 0.f, a2 = 0.f, a3 = 0.f;
  const int k0 = p4 * 512;
#pragma unroll 4
  for (int k = k0; k < k0 + 512; k += 4) {
    float4 hv = *(const float4*)(hp + k);
    float4 w0 = *(const float4*)(Wh2o + 0 * Hq + k);
    float4 w1 = *(const float4*)(Wh2o + 1 * Hq + k);
    float4 w2 = *(const float4*)(Wh2o + 2 * Hq + k);
    float4 w3 = *(const float4*)(Wh2o + 3 * Hq + k);
    DOT4(a0, hv, w0); DOT4(a1, hv, w1); DOT4(a2, hv, w2); DOT4(a3, hv, w3);
  }
  a0 += __shfl_xor(a0, 1); a1 += __shfl_xor(a1, 1);
  a2 += __shfl_xor(a2, 1); a3 += __shfl_xor(a3, 1);
  a0 += __shfl_xor(a0, 2); a1 += __shfl_xor(a1, 2);
  a2 += __shfl_xor(a2, 2); a3 += __shfl_xor(a3, 2);
  if (p4 == 0) {
    float m  = fmaxf(fmaxf(a0, a1), fmaxf(a2, a3));
    float e0 = expf(a0 - m), e1 = expf(a1 - m);
    float e2 = expf(a2 - m), e3 = expf(a3 - m);
    float inv = 1.0f / (e0 + e1 + e2 + e3);
    float* op = out_o + ((size_t)r * Tq + tp) * OUTq;
    op[0] = e0 * inv; op[1] = e1 * inv; op[2] = e2 * inv; op[3] = e3 * inv;
  }
}

// ---------------------------------------------------------------------------
// One step. 256 WGs x 512 threads (1 WG/CU, ~66KB LDS).
// Wave w: m-group mg=w&1 (16 rows), K-quarter kq=w>>1 (512 ks).
// Lane owns one column (col = TC*64 + lane); acc[16] rows.
// B[col][k] staged in LDS [64][33] (conflict-free b128 read/write);
// A rows read wave-uniformly straight from the h slab (scalar path, no LDS).
// Arithmetic order identical to R4 -> bitwise-identical output.
// ---------------------------------------------------------------------------
__global__ __launch_bounds__(512, 2) void rnn_step(
    const float* __restrict__ x, const float* __restrict__ noise,
    const float* __restrict__ Wi2h, const float* __restrict__ Wrec,
    const float* __restrict__ Wh2o, float* __restrict__ out_h,
    float* __restrict__ out_o, const float* __restrict__ slabP,
    float* __restrict__ slabT, int t)
{
  __shared__ float smem[SMEMF];

  const int wg  = blockIdx.x;
  const int tid = threadIdx.x;

  // XCD-chunked swizzle: XCD c owns col-tiles [4c,4c+4) -> 2MB Wrec panel L2-hot
  const int L  = (wg & 7) * 32 + (wg >> 3);
  const int TC = L >> 3;          // 0..31 col-tile
  const int TR = L & 7;           // 0..7  row-tile

  const int lane = tid & 63;
  const int wv   = __builtin_amdgcn_readfirstlane(tid >> 6);  // wave id 0..7
  const int mg   = wv & 1;        // row half of the 32-row tile
  const int kq   = wv >> 1;       // K-quarter
  const int kb   = kq * 512;
  const int col  = TC * 64 + lane;
  const int rowBase = TR * 32 + mg * 16;

  const float* hPrev = slabP ? slabP : (out_h + (size_t)(t > 0 ? t - 1 : 0) * Hq);
  const size_t hStr  = slabP ? (size_t)Hq : (size_t)Tq * Hq;

  // ---- B staging geometry: thread -> (col, kq, k-half-of-32) ----
  const int scol = tid & 63;
  const int sgrp = tid >> 6;
  const int skq  = sgrp >> 1;
  const int sph  = (sgrp & 1) * 16;
  const float* gB = Wrec + (size_t)(TC * 64 + scol) * Hq + skq * 512 + sph;
  float* bW0 = smem + (skq * 2) * 2112 + scol * 33 + sph;   // + buf*2112

  float4 s0, s1, s2, s3;
  if (t > 0) {                     // stage-0 loads first (overlap proj head)
    s0 = *(const float4*)(gB);      s1 = *(const float4*)(gB + 4);
    s2 = *(const float4*)(gB + 8);  s3 = *(const float4*)(gB + 12);
  }

  // ---- softmax head for step t-1, batch row wg (all 512 threads) ----
  if (t > 0) {
    float* ps = smem + 16896;
    const int i4 = tid * 4;
    float4 hv = *(const float4*)(hPrev + (size_t)wg * hStr + i4);
    float4 w0 = *(const float4*)(Wh2o + 0 * Hq + i4);
    float4 w1 = *(const float4*)(Wh2o + 1 * Hq + i4);
    float4 w2 = *(const float4*)(Wh2o + 2 * Hq + i4);
    float4 w3 = *(const float4*)(Wh2o + 3 * Hq + i4);
    float a0 = 0.f, a1 = 0.f, a2 = 0.f, a3 = 0.f;
    DOT4(a0, hv, w0); DOT4(a1, hv, w1); DOT4(a2, hv, w2); DOT4(a3, hv, w3);
#pragma unroll
    for (int m = 1; m <= 32; m <<= 1) {
      a0 += __shfl_xor(a0, m); a1 += __shfl_xor(a1, m);
      a2 += __shfl_xor(a2, m); a3 += __shfl_xor(a3, m);
    }
    if ((tid & 63) == 0) {
      ps[wv * 4 + 0] = a0; ps[wv * 4 + 1] = a1;
      ps[wv * 4 + 2] = a2; ps[wv * 4 + 3] = a3;
    }
    __syncthreads();
    if (tid == 0) {
      float q0 = 0.f, q1 = 0.f, q2 = 0.f, q3 = 0.f;
#pragma unroll
      for (int w = 0; w < 8; ++w) {          // fixed order
        q0 += ps[w * 4 + 0]; q1 += ps[w * 4 + 1];
        q2 += ps[w * 4 + 2]; q3 += ps[w * 4 + 3];
      }
      float m  = fmaxf(fmaxf(q0, q1), fmaxf(q2, q3));
      float e0 = expf(q0 - m), e1 = expf(q1 - m);
      float e2 = expf(q2 - m), e3 = expf(q3 - m);
      float inv = 1.0f / (e0 + e1 + e2 + e3);
      float* op = out_o + ((size_t)wg * Tq + (t - 1)) * OUTq;
      op[0] = e0 * inv; op[1] = e1 * inv; op[2] = e2 * inv; op[3] = e3 * inv;
    }
    __syncthreads();
  }

  float acc[16];
#pragma unroll
  for (int i = 0; i < 16; ++i) acc[i] = 0.f;

  const float* Abase = hPrev + (size_t)rowBase * hStr + kb;   // wave-uniform

  if (t > 0) {
    // prologue: write stage 0 (buf 0)
    *(float4*)(bW0)      = s0;  *(float4*)(bW0 + 4)  = s1;
    *(float4*)(bW0 + 8)  = s2;  *(float4*)(bW0 + 12) = s3;
    __syncthreads();

    for (int s = 0; s < NST; ++s) {
      const int buf = s & 1;
      if (s + 1 < NST) {                 // prefetch next B chunk into regs
        const float* g = gB + (s + 1) * BK;
        s0 = *(const float4*)(g);      s1 = *(const float4*)(g + 4);
        s2 = *(const float4*)(g + 8);  s3 = *(const float4*)(g + 12);
      }
      const float* bR = smem + (kq * 2 + buf) * 2112 + lane * 33;
      const float* aB = Abase + s * BK;
#pragma unroll
      for (int k4 = 0; k4 < BK; k4 += 4) {
        float4 b = *(const float4*)(bR + k4);
#pragma unroll
        for (int rr = 0; rr < 16; ++rr) {
          float4 a = *(const float4*)(aB + (size_t)rr * hStr + k4);
          DOT4(acc[rr], a, b);
        }
      }
      if (s + 1 < NST) {                 // write next stage (other buffer)
        float* w = bW0 + (buf ^ 1) * 2112;
        *(float4*)(w)      = s0;  *(float4*)(w + 4)  = s1;
        *(float4*)(w + 8)  = s2;  *(float4*)(w + 12) = s3;
      }
      __syncthreads();
    }
  }

  // ---- input projection, i-slice per quarter (same split/order as R4) ----
  {
    const int ilo = kq * 8;
    const int ihi = (kq == 3) ? INq : (ilo + 8);
    const float* xb = x + ((size_t)rowBase * Tq + t) * INq;
    const float* wi = Wi2h + (size_t)col * INq;
    const size_t xs = (size_t)Tq * INq;
    for (int i = ilo; i < ihi; ++i) {
      float w = wi[i];
#pragma unroll
      for (int rr = 0; rr < 16; ++rr)
        acc[rr] = fmaf(xb[(size_t)rr * xs + i], w, acc[rr]);
    }
  }

  // epilogue operand loads issued early (kq==0 waves only use them)
  const float* nzb = noise + ((size_t)t * Bq + rowBase) * Hq + col;
  const float* hpb = hPrev + (size_t)rowBase * hStr + col;

  // ---- split-K combine via LDS (fixed order q1,q2,q3) ----
  if (kq != 0) {
    float* rd = smem + ((size_t)((kq - 1) * 32 + mg * 16)) * 64 + lane;
#pragma unroll
    for (int rr = 0; rr < 16; ++rr) rd[rr * 64] = acc[rr];
  }
  __syncthreads();

  if (kq == 0) {
#pragma unroll
    for (int p = 0; p < 3; ++p) {
      const float* rd = smem + ((size_t)(p * 32 + mg * 16)) * 64 + lane;
#pragma unroll
      for (int rr = 0; rr < 16; ++rr) acc[rr] += rd[rr * 64];
    }
#pragma unroll
    for (int rr = 0; rr < 16; ++rr) {
      float nz = nzb[(size_t)rr * Hq];
      float hp = (t > 0) ? hpb[(size_t)rr * hStr] : 0.f;
      float o  = fmaf(fmaxf(acc[rr] + nz, 0.f), 0.1f, 0.9f * hp);
      out_h[((size_t)(rowBase + rr) * Tq + t) * Hq + col] = o;
      if (slabT) slabT[(size_t)(rowBase + rr) * Hq + col] = o;
    }
  }
}

extern "C" void kernel_launch(void* const* d_in, const int* in_sizes, int n_in,
                              void* d_out, int out_size, void* d_ws, size_t ws_size,
                              hipStream_t stream) {
  const float* x     = (const float*)d_in[0];
  const float* noise = (const float*)d_in[1];
  const float* Wi2h  = (const float*)d_in[2];
  const float* Wrec  = (const float*)d_in[3];
  const float* Wh2o  = (const float*)d_in[4];
  float* out_h = (float*)d_out;
  float* out_o = out_h + (size_t)Bq * Tq * Hq;

  const bool use_ws = ws_size >= (size_t)2 * Bq * Hq * sizeof(float);
  float* slab0 = (float*)d_ws;
  float* slab1 = slab0 + (size_t)Bq * Hq;

  for (int t = 0; t < Tq; ++t) {
    const float* sp = (t > 0 && use_ws) ? (((t - 1) & 1) ? slab1 : slab0) : nullptr;
    float*       st = use_ws ? ((t & 1) ? slab1 : slab0) : nullptr;
    rnn_step<<<256, 512, 0, stream>>>(x, noise, Wi2h, Wrec, Wh2o,
                                      out_h, out_o, sp, st, t);
  }
  const float* hb = use_ws ? ((Tq - 1) & 1 ? slab1 : slab0)
                           : (out_h + (size_t)(Tq - 1) * Hq);
  const size_t rs = use_ws ? (size_t)Hq : (size_t)Tq * Hq;
  proj_tail<<<4, 256, 0, stream>>>(hb, rs, Wh2o, out_o, Tq - 1);
}

// Round 7
// 32868.030 us; speedup vs baseline: 5.8464x; 5.8464x over previous
//
#include <hip/hip_runtime.h>
#include <math.h>

#define Bq 256
#define Tq 200
#define INq 33
#define Hq 2048
#define OUTq 4

#define BK 32
#define NST 16          // stages per K-quarter: 512/32

#define DOT4(ACC, Av, Bv) \
  ACC = fmaf((Av).x, (Bv).x, ACC); ACC = fmaf((Av).y, (Bv).y, ACC); \
  ACC = fmaf((Av).z, (Bv).z, ACC); ACC = fmaf((Av).w, (Bv).w, ACC)

// LDS (floats): Bbuf[kq][buf] = [64 cols][33] at (kq*2+buf)*2112 -> 16896
// combine region (post-K-loop, overlays B bufs): 6144 at 0
// proj scratch: 32 at 16896
#define SMEMF 16928

#define REP16(M) M(0) M(1) M(2) M(3) M(4) M(5) M(6) M(7) \
                 M(8) M(9) M(10) M(11) M(12) M(13) M(14) M(15)

// ---------------------------------------------------------------------------
// tail: out_o[r, tp, :] = softmax(h_row @ Wh2o^T) for the final step
// ---------------------------------------------------------------------------
__global__ __launch_bounds__(256) void proj_tail(
    const float* __restrict__ hbase, size_t rstride,
    const float* __restrict__ Wh2o, float* __restrict__ out_o, int tp)
{
  const int tid = threadIdx.x;
  const int r  = blockIdx.x * 64 + (tid >> 2);
  const int p4 = tid & 3;
  const float* hp = hbase + (size_t)r * rstride;
  float a0 = 0.f, a1 = 0.f, a2 = 0.f, a3 = 0.f;
  const int k0 = p4 * 512;
#pragma unroll 4
  for (int k = k0; k < k0 + 512; k += 4) {
    float4 hv = *(const float4*)(hp + k);
    float4 w0 = *(const float4*)(Wh2o + 0 * Hq + k);
    float4 w1 = *(const float4*)(Wh2o + 1 * Hq + k);
    float4 w2 = *(const float4*)(Wh2o + 2 * Hq + k);
    float4 w3 = *(const float4*)(Wh2o + 3 * Hq + k);
    DOT4(a0, hv, w0); DOT4(a1, hv, w1); DOT4(a2, hv, w2); DOT4(a3, hv, w3);
  }
  a0 += __shfl_xor(a0, 1); a1 += __shfl_xor(a1, 1);
  a2 += __shfl_xor(a2, 1); a3 += __shfl_xor(a3, 1);
  a0 += __shfl_xor(a0, 2); a1 += __shfl_xor(a1, 2);
  a2 += __shfl_xor(a2, 2); a3 += __shfl_xor(a3, 2);
  if (p4 == 0) {
    float m  = fmaxf(fmaxf(a0, a1), fmaxf(a2, a3));
    float e0 = expf(a0 - m), e1 = expf(a1 - m);
    float e2 = expf(a2 - m), e3 = expf(a3 - m);
    float inv = 1.0f / (e0 + e1 + e2 + e3);
    float* op = out_o + ((size_t)r * Tq + tp) * OUTq;
    op[0] = e0 * inv; op[1] = e1 * inv; op[2] = e2 * inv; op[3] = e3 * inv;
  }
}

// ---------------------------------------------------------------------------
// One step. 256 WGs x 512 threads.
// Wave w: row-half mg=w&1 (16 rows), K-quarter kq=w>>1 (512 ks).
// Lane owns one column; acc = 16 rows (named regs). A rows are wave-uniform
// broadcast loads from the contiguous slab (compile-time stride -> cheap
// addressing, 16 named pointers). B staged in LDS [64][33] (conflict-free).
// Arithmetic order identical to R4/R6 -> bitwise-identical output.
// ---------------------------------------------------------------------------
template<bool SLAB>
__global__ __launch_bounds__(512, 1) void rnn_step(
    const float* __restrict__ x, const float* __restrict__ noise,
    const float* __restrict__ Wi2h, const float* __restrict__ Wrec,
    const float* __restrict__ Wh2o, float* __restrict__ out_h,
    float* __restrict__ out_o, const float* __restrict__ slabP,
    float* __restrict__ slabT, int t)
{
  constexpr size_t HSTR = SLAB ? (size_t)Hq : (size_t)Tq * Hq;
  __shared__ float smem[SMEMF];

  const int wg  = blockIdx.x;
  const int tid = threadIdx.x;

  // XCD-chunked swizzle: XCD c owns col-tiles [4c,4c+4) -> Wrec panel L2-hot
  const int L  = (wg & 7) * 32 + (wg >> 3);
  const int TC = L >> 3;          // 0..31 col-tile
  const int TR = L & 7;           // 0..7  row-tile

  const int lane = tid & 63;
  const int wv   = __builtin_amdgcn_readfirstlane(tid >> 6);  // wave 0..7
  const int mg   = wv & 1;
  const int kq   = wv >> 1;
  const int kb   = kq * 512;
  const int col  = TC * 64 + lane;
  const int rowBase = TR * 32 + mg * 16;

  const float* hPrev = SLAB ? slabP
                            : (out_h + (size_t)(t > 0 ? t - 1 : 0) * Hq);

  // ---- B staging geometry ----
  const int scol = tid & 63;
  const int sgrp = tid >> 6;
  const int skq  = sgrp >> 1;
  const int sph  = (sgrp & 1) * 16;
  const float* gB = Wrec + (size_t)(TC * 64 + scol) * Hq + skq * 512 + sph;
  float* bW0 = smem + (skq * 2) * 2112 + scol * 33 + sph;   // + buf*2112

  float4 s0, s1, s2, s3;
  if (t > 0) {                     // stage-0 loads first (overlap proj head)
    s0 = *(const float4*)(gB);      s1 = *(const float4*)(gB + 4);
    s2 = *(const float4*)(gB + 8);  s3 = *(const float4*)(gB + 12);
  }

  // ---- softmax head for step t-1, batch row wg ----
  if (t > 0) {
    float* ps = smem + 16896;
    const int i4 = tid * 4;
    float4 hv = *(const float4*)(hPrev + (size_t)wg * HSTR + i4);
    float4 w0 = *(const float4*)(Wh2o + 0 * Hq + i4);
    float4 w1 = *(const float4*)(Wh2o + 1 * Hq + i4);
    float4 w2 = *(const float4*)(Wh2o + 2 * Hq + i4);
    float4 w3 = *(const float4*)(Wh2o + 3 * Hq + i4);
    float a0 = 0.f, a1 = 0.f, a2 = 0.f, a3 = 0.f;
    DOT4(a0, hv, w0); DOT4(a1, hv, w1); DOT4(a2, hv, w2); DOT4(a3, hv, w3);
#pragma unroll
    for (int m = 1; m <= 32; m <<= 1) {
      a0 += __shfl_xor(a0, m); a1 += __shfl_xor(a1, m);
      a2 += __shfl_xor(a2, m); a3 += __shfl_xor(a3, m);
    }
    if ((tid & 63) == 0) {
      ps[wv * 4 + 0] = a0; ps[wv * 4 + 1] = a1;
      ps[wv * 4 + 2] = a2; ps[wv * 4 + 3] = a3;
    }
    __syncthreads();
    if (tid == 0) {
      float q0 = 0.f, q1 = 0.f, q2 = 0.f, q3 = 0.f;
#pragma unroll
      for (int w = 0; w < 8; ++w) {          // fixed order
        q0 += ps[w * 4 + 0]; q1 += ps[w * 4 + 1];
        q2 += ps[w * 4 + 2]; q3 += ps[w * 4 + 3];
      }
      float m  = fmaxf(fmaxf(q0, q1), fmaxf(q2, q3));
      float e0 = expf(q0 - m), e1 = expf(q1 - m);
      float e2 = expf(q2 - m), e3 = expf(q3 - m);
      float inv = 1.0f / (e0 + e1 + e2 + e3);
      float* op = out_o + ((size_t)wg * Tq + (t - 1)) * OUTq;
      op[0] = e0 * inv; op[1] = e1 * inv; op[2] = e2 * inv; op[3] = e3 * inv;
    }
    __syncthreads();
  }

#define DECL_ACC(i) float acc##i = 0.f;
  REP16(DECL_ACC)
#undef DECL_ACC

  if (t > 0) {
    // 16 wave-uniform row pointers, compile-time stride
#define DECL_AR(i) const float* ar##i = hPrev + (size_t)(rowBase + i) * HSTR + kb;
    REP16(DECL_AR)
#undef DECL_AR

    // prologue: write stage 0 (buf 0)
    *(float4*)(bW0)      = s0;  *(float4*)(bW0 + 4)  = s1;
    *(float4*)(bW0 + 8)  = s2;  *(float4*)(bW0 + 12) = s3;
    __syncthreads();

    for (int s = 0; s < NST; ++s) {
      const int buf = s & 1;
      if (s + 1 < NST) {                 // prefetch next B chunk into regs
        const float* g = gB + (s + 1) * BK;
        s0 = *(const float4*)(g);      s1 = *(const float4*)(g + 4);
        s2 = *(const float4*)(g + 8);  s3 = *(const float4*)(g + 12);
      }
      const float* bR = smem + (kq * 2 + buf) * 2112 + lane * 33;
#pragma unroll
      for (int k4 = 0; k4 < BK; k4 += 4) {
        float4 b = *(const float4*)(bR + k4);
#define ROWFMA(i) { float4 a_ = *(const float4*)(ar##i + k4); DOT4(acc##i, a_, b); }
        REP16(ROWFMA)
#undef ROWFMA
      }
#define ADV(i) ar##i += BK;
      REP16(ADV)
#undef ADV
      if (s + 1 < NST) {                 // write next stage (other buffer)
        float* w = bW0 + (buf ^ 1) * 2112;
        *(float4*)(w)      = s0;  *(float4*)(w + 4)  = s1;
        *(float4*)(w + 8)  = s2;  *(float4*)(w + 12) = s3;
      }
      __syncthreads();
    }
  }

  // ---- input projection, i-slice per quarter (same split/order as R4/R6) ----
  {
    const int ilo = kq * 8;
    const int ihi = (kq == 3) ? INq : (ilo + 8);
    const float* xb = x + ((size_t)rowBase * Tq + t) * INq;
    const float* wi = Wi2h + (size_t)col * INq;
    const size_t xs = (size_t)Tq * INq;
    for (int iX = ilo; iX < ihi; ++iX) {
      float wv_ = wi[iX];
#define XP(i) acc##i = fmaf(xb[(size_t)(i) * xs + iX], wv_, acc##i);
      REP16(XP)
#undef XP
    }
  }

  // ---- split-K combine via LDS (fixed order q1,q2,q3) ----
  if (kq != 0) {
    float* rd = smem + ((size_t)((kq - 1) * 32 + mg * 16)) * 64 + lane;
#define CWR(i) rd[(i) * 64] = acc##i;
    REP16(CWR)
#undef CWR
  }
  __syncthreads();

  if (kq == 0) {
#pragma unroll
    for (int p = 0; p < 3; ++p) {
      const float* rd2 = smem + ((size_t)(p * 32 + mg * 16)) * 64 + lane;
#define CRD(i) acc##i += rd2[(i) * 64];
      REP16(CRD)
#undef CRD
    }
    const float* nzb = noise + ((size_t)t * Bq + rowBase) * Hq + col;
    const float* hpb = hPrev + (size_t)rowBase * HSTR + col;
#define EPI(i) { \
    float nz_ = nzb[(size_t)(i) * Hq]; \
    float hp_ = (t > 0) ? hpb[(size_t)(i) * HSTR] : 0.f; \
    float o_  = fmaf(fmaxf(acc##i + nz_, 0.f), 0.1f, 0.9f * hp_); \
    out_h[((size_t)(rowBase + (i)) * Tq + t) * Hq + col] = o_; \
    if (SLAB) slabT[(size_t)(rowBase + (i)) * Hq + col] = o_; }
    REP16(EPI)
#undef EPI
  }
}

extern "C" void kernel_launch(void* const* d_in, const int* in_sizes, int n_in,
                              void* d_out, int out_size, void* d_ws, size_t ws_size,
                              hipStream_t stream) {
  const float* x     = (const float*)d_in[0];
  const float* noise = (const float*)d_in[1];
  const float* Wi2h  = (const float*)d_in[2];
  const float* Wrec  = (const float*)d_in[3];
  const float* Wh2o  = (const float*)d_in[4];
  float* out_h = (float*)d_out;
  float* out_o = out_h + (size_t)Bq * Tq * Hq;

  const bool use_ws = ws_size >= (size_t)2 * Bq * Hq * sizeof(float);
  float* slab0 = (float*)d_ws;
  float* slab1 = slab0 + (size_t)Bq * Hq;

  if (use_ws) {
    for (int t = 0; t < Tq; ++t) {
      const float* sp = (t > 0) ? (((t - 1) & 1) ? slab1 : slab0) : nullptr;
      float*       st = (t & 1) ? slab1 : slab0;
      rnn_step<true><<<256, 512, 0, stream>>>(x, noise, Wi2h, Wrec, Wh2o,
                                              out_h, out_o, sp, st, t);
    }
    const float* hb = ((Tq - 1) & 1) ? slab1 : slab0;
    proj_tail<<<4, 256, 0, stream>>>(hb, (size_t)Hq, Wh2o, out_o, Tq - 1);
  } else {
    for (int t = 0; t < Tq; ++t) {
      rnn_step<false><<<256, 512, 0, stream>>>(x, noise, Wi2h, Wrec, Wh2o,
                                               out_h, out_o, nullptr, nullptr, t);
    }
    proj_tail<<<4, 256, 0, stream>>>(out_h + (size_t)(Tq - 1) * Hq,
                                     (size_t)Tq * Hq, Wh2o, out_o, Tq - 1);
  }
}